// Round 9
// baseline (438.941 us; speedup 1.0000x reference)
//
#include <hip/hip_runtime.h>
#include <math.h>

#define NP 3136
#define NC 256
#define NB 16
#define HH 56
#define OW 224

// ---------------- Stage 1: Mahalanobis distance (R2 version, measured best) --
__device__ __forceinline__ void rowstep(const float4 mv, const int c,
                                        const float (&dreg)[4][16], float (&z)[16],
                                        const float (*dc_lds)[20]) {
  float s[16];
#pragma unroll
  for (int b = 0; b < 16; ++b) s[b] = mv.x * dreg[0][b];
#pragma unroll
  for (int b = 0; b < 16; ++b) s[b] = fmaf(mv.y, dreg[1][b], s[b]);
#pragma unroll
  for (int b = 0; b < 16; ++b) s[b] = fmaf(mv.z, dreg[2][b], s[b]);
#pragma unroll
  for (int b = 0; b < 16; ++b) s[b] = fmaf(mv.w, dreg[3][b], s[b]);
#pragma unroll
  for (int q = 0; q < 4; ++q) {
    const float4 dc = *reinterpret_cast<const float4*>(&dc_lds[c][4 * q]);
    z[4 * q + 0] = fmaf(dc.x, s[4 * q + 0], z[4 * q + 0]);
    z[4 * q + 1] = fmaf(dc.y, s[4 * q + 1], z[4 * q + 1]);
    z[4 * q + 2] = fmaf(dc.z, s[4 * q + 2], z[4 * q + 2]);
    z[4 * q + 3] = fmaf(dc.w, s[4 * q + 3], z[4 * q + 3]);
  }
}

__global__ __launch_bounds__(256) void k_dist(const float* __restrict__ emb,
                                              const float* __restrict__ means,
                                              const float* __restrict__ icov,
                                              float* __restrict__ dist) {
  __shared__ float dc_lds[NC][20];      // [c][b]+pad: broadcast reads (hot loop)
  __shared__ float db_lds[NB][NC + 8];  // [b][c]+pad: conflict-free dreg load
  __shared__ float zbuf[4][16];

  const int bid = blockIdx.x;
  const int p = (bid & 7) * (NP >> 3) + (bid >> 3);  // XCD swizzle (3136 % 8 == 0)
  const int t = threadIdx.x;
  const int lane = t & 63;
  const int wv = t >> 6;

  {
    const int c = t;
    const float mn = means[(size_t)p * NC + c];
    const float* ep = emb + (size_t)c * NP + p;
    float d[16];
#pragma unroll
    for (int b = 0; b < 16; ++b) d[b] = ep[(size_t)b * (NC * NP)] - mn;
#pragma unroll
    for (int q = 0; q < 4; ++q) {
      *reinterpret_cast<float4*>(&dc_lds[c][4 * q]) =
          make_float4(d[4 * q], d[4 * q + 1], d[4 * q + 2], d[4 * q + 3]);
    }
#pragma unroll
    for (int b = 0; b < 16; ++b) db_lds[b][c] = d[b];
  }
  __syncthreads();

  float dreg[4][16];
#pragma unroll
  for (int b = 0; b < 16; ++b) {
    const float4 v = *reinterpret_cast<const float4*>(&db_lds[b][4 * lane]);
    dreg[0][b] = v.x; dreg[1][b] = v.y; dreg[2][b] = v.z; dreg[3][b] = v.w;
  }

  float z[16];
#pragma unroll
  for (int b = 0; b < 16; ++b) z[b] = 0.f;

  const float* mbase = icov + (size_t)p * (NC * NC) + (size_t)(wv * 64) * NC + 4 * lane;
#define LOADM(r) (*reinterpret_cast<const float4*>(mbase + (size_t)(r) * NC))

  float4 m0 = LOADM(0), m1 = LOADM(1), m2 = LOADM(2), m3 = LOADM(3);
  for (int rb = 0; rb < 64; rb += 4) {
    const int r4 = (rb + 4 < 64) ? rb + 4 : 63;
    const int r5 = (rb + 5 < 64) ? rb + 5 : 63;
    const int r6 = (rb + 6 < 64) ? rb + 6 : 63;
    const int r7 = (rb + 7 < 64) ? rb + 7 : 63;
    const float4 n0 = LOADM(r4);
    const float4 n1 = LOADM(r5);
    const float4 n2 = LOADM(r6);
    const float4 n3 = LOADM(r7);
    rowstep(m0, wv * 64 + rb + 0, dreg, z, dc_lds);
    rowstep(m1, wv * 64 + rb + 1, dreg, z, dc_lds);
    rowstep(m2, wv * 64 + rb + 2, dreg, z, dc_lds);
    rowstep(m3, wv * 64 + rb + 3, dreg, z, dc_lds);
    m0 = n0; m1 = n1; m2 = n2; m3 = n3;
  }
#undef LOADM

#pragma unroll
  for (int b = 0; b < 16; ++b) {
    float v = z[b];
#pragma unroll
    for (int off = 32; off > 0; off >>= 1) v += __shfl_xor(v, off, 64);
    z[b] = v;
  }
  if (lane == 0) {
#pragma unroll
    for (int b = 0; b < 16; ++b) zbuf[wv][b] = z[b];
  }
  __syncthreads();
  if (t < 16) {
    const float d2 = zbuf[0][t] + zbuf[1][t] + zbuf[2][t] + zbuf[3][t];
    dist[(size_t)t * NP + p] = sqrtf(d2);
  }
}

// ---------------- Stage 2a: fused bilinear-resize + row gaussian blur --------
__global__ __launch_bounds__(256) void k_rowblur(const float* __restrict__ dist,
                                                 float* __restrict__ out,
                                                 unsigned int* __restrict__ mm) {
  __shared__ float w[33];
  __shared__ float row[256];
  const int t = threadIdx.x;
  const int by = blockIdx.x;  // b*224 + y
  const int b = by / OW, y = by - b * OW;
  if (by == 0 && t == 0) { mm[0] = 0x7f800000u; mm[1] = 0u; }  // init for colblur
  if (t < 33) {
    const float d = (float)(t - 16);
    w[t] = expf(-d * d * (1.f / 32.f));
  }
  int xi = t - 16;  // [-16, 239] -> reflect into [0, 224)
  xi = (xi < 0) ? (-xi - 1) : xi;
  xi = (xi >= OW) ? (2 * OW - 1 - xi) : xi;
  const float sy = y * 0.25f - 0.375f;
  const float sx = xi * 0.25f - 0.375f;
  const int y0 = (int)floorf(sy), x0 = (int)floorf(sx);
  const float fy = sy - (float)y0, fx = sx - (float)x0;
  const int y0c = y0 < 0 ? 0 : (y0 > HH - 1 ? HH - 1 : y0);
  const int y1c = (y0 + 1) > HH - 1 ? HH - 1 : (y0 + 1 < 0 ? 0 : y0 + 1);
  const int x0c = x0 < 0 ? 0 : (x0 > HH - 1 ? HH - 1 : x0);
  const int x1c = (x0 + 1) > HH - 1 ? HH - 1 : (x0 + 1 < 0 ? 0 : x0 + 1);
  const float* db = dist + (size_t)b * NP;
  const float v00 = db[y0c * HH + x0c], v01 = db[y0c * HH + x1c];
  const float v10 = db[y1c * HH + x0c], v11 = db[y1c * HH + x1c];
  const float v0 = v00 + fx * (v01 - v00);
  const float v1 = v10 + fx * (v11 - v10);
  row[t] = v0 + fy * (v1 - v0);
  __syncthreads();
  if (t < OW) {
    float a = 0.f;
#pragma unroll
    for (int k = 0; k < 33; ++k) a = fmaf(w[k], row[t + k], a);
    out[(size_t)by * OW + t] = a;
  }
}

// ---------------- Stage 2b: column gaussian blur + global min/max ------------
__global__ __launch_bounds__(256) void k_colblur(const float* __restrict__ in,
                                                 float* __restrict__ out,
                                                 unsigned int* __restrict__ mm) {
  __shared__ float w[33];
  __shared__ float red[4][2];
  const int t = threadIdx.x;
  const int by = blockIdx.x;  // b*224 + y
  const int b = by / OW, y = by - b * OW;
  if (t < 33) {
    const float d = (float)(t - 16);
    w[t] = expf(-d * d * (1.f / 32.f));
  }
  __syncthreads();
  float a = 0.f;
  const float* bp = in + (size_t)b * OW * OW;
  if (t < OW) {
#pragma unroll
    for (int k = 0; k < 33; ++k) {
      int yi = y + k - 16;
      yi = (yi < 0) ? (-yi - 1) : yi;
      yi = (yi >= OW) ? (2 * OW - 1 - yi) : yi;
      a = fmaf(w[k], bp[(size_t)yi * OW + t], a);
    }
    out[(size_t)by * OW + t] = a;
  }
  float mnv = (t < OW) ? a : 3.0e38f;
  float mxv = (t < OW) ? a : 0.f;
#pragma unroll
  for (int off = 32; off > 0; off >>= 1) {
    mnv = fminf(mnv, __shfl_xor(mnv, off, 64));
    mxv = fmaxf(mxv, __shfl_xor(mxv, off, 64));
  }
  const int lane = t & 63, wv = t >> 6;
  if (lane == 0) { red[wv][0] = mnv; red[wv][1] = mxv; }
  __syncthreads();
  if (t == 0) {
    const float m0 = fminf(fminf(red[0][0], red[1][0]), fminf(red[2][0], red[3][0]));
    const float m1 = fmaxf(fmaxf(red[0][1], red[1][1]), fmaxf(red[2][1], red[3][1]));
    atomicMin(&mm[0], __float_as_uint(m0));
    atomicMax(&mm[1], __float_as_uint(m1));
  }
}

// ---------------- Stage 2c: normalize (float4) ----------------
__global__ __launch_bounds__(256) void k_norm(const float4* __restrict__ in,
                                              const unsigned int* __restrict__ mm,
                                              float4* __restrict__ out) {
  const int i = blockIdx.x * 256 + threadIdx.x;  // 200704 float4s exactly
  const float mn = __uint_as_float(mm[0]);
  const float mx = __uint_as_float(mm[1]);
  const float inv = 1.f / (mx - mn);
  const float4 v = in[i];
  out[i] = make_float4((v.x - mn) * inv, (v.y - mn) * inv,
                       (v.z - mn) * inv, (v.w - mn) * inv);
}

extern "C" void kernel_launch(void* const* d_in, const int* in_sizes, int n_in,
                              void* d_out, int out_size, void* d_ws, size_t ws_size,
                              hipStream_t stream) {
  const float* emb = (const float*)d_in[0];    // [16,256,3136]
  const float* means = (const float*)d_in[1];  // [3136,256]
  const float* icov = (const float*)d_in[2];   // [3136,256,256]
  float* out = (float*)d_out;                  // [16,224,224]

  char* ws = (char*)d_ws;
  float* dist = (float*)ws;                        // 16*3136 floats   @ 0
  float* tmp1 = (float*)(ws + 204800);             // 16*224*224 floats
  unsigned int* mm = (unsigned int*)(ws + 3416064);
  float* dist2 = (float*)(ws + 4194304);           // dead scratch for timing dup

  // MEASUREMENT ROUND: duplicate k_dist into dead scratch. total - 270 = dur(k_dist).
  k_dist<<<NP, 256, 0, stream>>>(emb, means, icov, dist2);
  k_dist<<<NP, 256, 0, stream>>>(emb, means, icov, dist);
  k_rowblur<<<NB * OW, 256, 0, stream>>>(dist, out, mm);   // out as scratch
  k_colblur<<<NB * OW, 256, 0, stream>>>(out, tmp1, mm);
  k_norm<<<NB * OW * OW / 1024, 256, 0, stream>>>((const float4*)tmp1, mm,
                                                  (float4*)out);
}

// Round 10
// 205.950 us; speedup vs baseline: 2.1313x; 2.1313x over previous
//
#include <hip/hip_runtime.h>
#include <math.h>

#define NP 3136
#define NC 256
#define NB 16
#define HH 56
#define OW 224

// ---------------- Stage 1: Mahalanobis distance (R2 version, measured best) --
__device__ __forceinline__ void rowstep(const float4 mv, const int c,
                                        const float (&dreg)[4][16], float (&z)[16],
                                        const float (*dc_lds)[20]) {
  float s[16];
#pragma unroll
  for (int b = 0; b < 16; ++b) s[b] = mv.x * dreg[0][b];
#pragma unroll
  for (int b = 0; b < 16; ++b) s[b] = fmaf(mv.y, dreg[1][b], s[b]);
#pragma unroll
  for (int b = 0; b < 16; ++b) s[b] = fmaf(mv.z, dreg[2][b], s[b]);
#pragma unroll
  for (int b = 0; b < 16; ++b) s[b] = fmaf(mv.w, dreg[3][b], s[b]);
#pragma unroll
  for (int q = 0; q < 4; ++q) {
    const float4 dc = *reinterpret_cast<const float4*>(&dc_lds[c][4 * q]);
    z[4 * q + 0] = fmaf(dc.x, s[4 * q + 0], z[4 * q + 0]);
    z[4 * q + 1] = fmaf(dc.y, s[4 * q + 1], z[4 * q + 1]);
    z[4 * q + 2] = fmaf(dc.z, s[4 * q + 2], z[4 * q + 2]);
    z[4 * q + 3] = fmaf(dc.w, s[4 * q + 3], z[4 * q + 3]);
  }
}

__global__ __launch_bounds__(256) void k_dist(const float* __restrict__ emb,
                                              const float* __restrict__ means,
                                              const float* __restrict__ icov,
                                              float* __restrict__ dist,
                                              unsigned int* __restrict__ mm) {
  __shared__ float dc_lds[NC][20];      // [c][b]+pad: broadcast reads (hot loop)
  __shared__ float db_lds[NB][NC + 8];  // [b][c]+pad: conflict-free dreg load
  __shared__ float zbuf[4][16];

  const int bid = blockIdx.x;
  const int p = (bid & 7) * (NP >> 3) + (bid >> 3);  // XCD swizzle (3136 % 8 == 0)
  const int t = threadIdx.x;
  const int lane = t & 63;
  const int wv = t >> 6;

  if (bid == 0 && t == 0) { mm[0] = 0x7f800000u; mm[1] = 0u; }  // init for k_blur

  {
    const int c = t;
    const float mn = means[(size_t)p * NC + c];
    const float* ep = emb + (size_t)c * NP + p;
    float d[16];
#pragma unroll
    for (int b = 0; b < 16; ++b) d[b] = ep[(size_t)b * (NC * NP)] - mn;
#pragma unroll
    for (int q = 0; q < 4; ++q) {
      *reinterpret_cast<float4*>(&dc_lds[c][4 * q]) =
          make_float4(d[4 * q], d[4 * q + 1], d[4 * q + 2], d[4 * q + 3]);
    }
#pragma unroll
    for (int b = 0; b < 16; ++b) db_lds[b][c] = d[b];
  }
  __syncthreads();

  float dreg[4][16];
#pragma unroll
  for (int b = 0; b < 16; ++b) {
    const float4 v = *reinterpret_cast<const float4*>(&db_lds[b][4 * lane]);
    dreg[0][b] = v.x; dreg[1][b] = v.y; dreg[2][b] = v.z; dreg[3][b] = v.w;
  }

  float z[16];
#pragma unroll
  for (int b = 0; b < 16; ++b) z[b] = 0.f;

  const float* mbase = icov + (size_t)p * (NC * NC) + (size_t)(wv * 64) * NC + 4 * lane;
#define LOADM(r) (*reinterpret_cast<const float4*>(mbase + (size_t)(r) * NC))

  float4 m0 = LOADM(0), m1 = LOADM(1), m2 = LOADM(2), m3 = LOADM(3);
  for (int rb = 0; rb < 64; rb += 4) {
    const int r4 = (rb + 4 < 64) ? rb + 4 : 63;
    const int r5 = (rb + 5 < 64) ? rb + 5 : 63;
    const int r6 = (rb + 6 < 64) ? rb + 6 : 63;
    const int r7 = (rb + 7 < 64) ? rb + 7 : 63;
    const float4 n0 = LOADM(r4);
    const float4 n1 = LOADM(r5);
    const float4 n2 = LOADM(r6);
    const float4 n3 = LOADM(r7);
    rowstep(m0, wv * 64 + rb + 0, dreg, z, dc_lds);
    rowstep(m1, wv * 64 + rb + 1, dreg, z, dc_lds);
    rowstep(m2, wv * 64 + rb + 2, dreg, z, dc_lds);
    rowstep(m3, wv * 64 + rb + 3, dreg, z, dc_lds);
    m0 = n0; m1 = n1; m2 = n2; m3 = n3;
  }
#undef LOADM

#pragma unroll
  for (int b = 0; b < 16; ++b) {
    float v = z[b];
#pragma unroll
    for (int off = 32; off > 0; off >>= 1) v += __shfl_xor(v, off, 64);
    z[b] = v;
  }
  if (lane == 0) {
#pragma unroll
    for (int b = 0; b < 16; ++b) zbuf[wv][b] = z[b];
  }
  __syncthreads();
  if (t < 16) {
    const float d2 = zbuf[0][t] + zbuf[1][t] + zbuf[2][t] + zbuf[3][t];
    dist[(size_t)t * NP + p] = sqrtf(d2);
  }
}

// ---------------- Stage 2: fused resize + row/col gaussian + min/max ---------
// The whole chain (bilinear 56->224, 33-tap x-blur, 33-tap y-blur with
// reflection) is linear & separable: out = Cy * dist * Cx^T, where Cx/Cy are
// 224x56 composed coefficient matrices with <=13 nonzeros per row (built in
// LDS, reflection+edge-clamp folded in). Unnormalized gaussian weights: the
// constant cancels in the final min-max normalization.
// Grid: 16 images x 4 column strips of 56. Block 256 threads.
__global__ __launch_bounds__(256) void k_blur(const float* __restrict__ dist,
                                              float* __restrict__ outb,
                                              unsigned int* __restrict__ mm) {
  __shared__ float w[33];
  __shared__ float ld[56 * 56];       // source image tile
  __shared__ float ccx[56][13];       // x-composed coeffs for this strip
  __shared__ float ccy[224][13];      // y-composed coeffs
  __shared__ int xlo[56];
  __shared__ int ylo[224];
  __shared__ float rb[56][57];        // ld * Cx^T (rows = source u)
  __shared__ float red[4][2];

  const int t = threadIdx.x;
  const int b = blockIdx.x >> 2;
  const int x0 = (blockIdx.x & 3) * 56;

  if (t < 33) {
    const float d = (float)(t - 16);
    w[t] = expf(-d * d * (1.f / 32.f));
  }
  for (int i = t; i < 56 * 56; i += 256) ld[i] = dist[(size_t)b * NP + i];
  __syncthreads();

  // build Cy rows (one thread per output y)
  if (t < 224) {
    const int y = t;
    int lo = 56;
    for (int j = 0; j < 33; ++j) {
      int yy = y + j - 16;
      yy = (yy < 0) ? (-1 - yy) : (yy >= 224 ? 447 - yy : yy);
      const int U = (int)floorf(yy * 0.25f - 0.375f);
      const int u0c = U < 0 ? 0 : U;
      lo = lo < u0c ? lo : u0c;
    }
    ylo[y] = lo;
#pragma unroll
    for (int n = 0; n < 13; ++n) ccy[y][n] = 0.f;
    for (int j = 0; j < 33; ++j) {
      int yy = y + j - 16;
      yy = (yy < 0) ? (-1 - yy) : (yy >= 224 ? 447 - yy : yy);
      const float sy = yy * 0.25f - 0.375f;
      const int U = (int)floorf(sy);
      const float fy = sy - (float)U;
      const int u0c = U < 0 ? 0 : U;
      const int u1c = (U + 1) > 55 ? 55 : (U + 1);
      ccy[y][u0c - lo] += w[j] * (1.f - fy);
      ccy[y][u1c - lo] += w[j] * fy;
    }
  }
  // build Cx rows for this strip (one thread per strip column)
  if (t < 56) {
    const int x = x0 + t;
    int lo = 56;
    for (int j = 0; j < 33; ++j) {
      int xx = x + j - 16;
      xx = (xx < 0) ? (-1 - xx) : (xx >= 224 ? 447 - xx : xx);
      const int U = (int)floorf(xx * 0.25f - 0.375f);
      const int u0c = U < 0 ? 0 : U;
      lo = lo < u0c ? lo : u0c;
    }
    xlo[t] = lo;
#pragma unroll
    for (int n = 0; n < 13; ++n) ccx[t][n] = 0.f;
    for (int j = 0; j < 33; ++j) {
      int xx = x + j - 16;
      xx = (xx < 0) ? (-1 - xx) : (xx >= 224 ? 447 - xx : xx);
      const float sx = xx * 0.25f - 0.375f;
      const int U = (int)floorf(sx);
      const float fx = sx - (float)U;
      const int u0c = U < 0 ? 0 : U;
      const int u1c = (U + 1) > 55 ? 55 : (U + 1);
      ccx[t][u0c - lo] += w[j] * (1.f - fx);
      ccx[t][u1c - lo] += w[j] * fx;
    }
  }
  __syncthreads();

  // rb[u][lx] = sum_v Cx[lx][v] * ld[u][v]
  for (int i = t; i < 56 * 56; i += 256) {
    const int u = i / 56, lx = i - 56 * u;
    const int lo = xlo[lx];
    const float* lrow = &ld[u * 56];
    float acc = 0.f;
#pragma unroll
    for (int n = 0; n < 13; ++n) {
      int v = lo + n;
      v = v > 55 ? 55 : v;  // coeff is 0 there; clamp keeps the read in-tile
      acc = fmaf(ccx[lx][n], lrow[v], acc);
    }
    rb[u][lx] = acc;
  }
  __syncthreads();

  // out[y][x0+lx] = sum_u Cy[y][u] * rb[u][lx]; track block min/max
  float mnv = 1e30f, mxv = 0.f;
  if (t < 224) {
    const int y = t;
    const int lo = ylo[y];
    float* orow = outb + ((size_t)b * OW + y) * OW + x0;
    for (int c = 0; c < 7; ++c) {
      float a0 = 0.f, a1 = 0.f, a2 = 0.f, a3 = 0.f,
            a4 = 0.f, a5 = 0.f, a6 = 0.f, a7 = 0.f;
#pragma unroll
      for (int n = 0; n < 13; ++n) {
        int u = lo + n;
        u = u > 55 ? 55 : u;
        const float cy = ccy[y][n];
        const float* rrow = &rb[u][c * 8];
        a0 = fmaf(cy, rrow[0], a0); a1 = fmaf(cy, rrow[1], a1);
        a2 = fmaf(cy, rrow[2], a2); a3 = fmaf(cy, rrow[3], a3);
        a4 = fmaf(cy, rrow[4], a4); a5 = fmaf(cy, rrow[5], a5);
        a6 = fmaf(cy, rrow[6], a6); a7 = fmaf(cy, rrow[7], a7);
      }
      orow[c * 8 + 0] = a0; orow[c * 8 + 1] = a1;
      orow[c * 8 + 2] = a2; orow[c * 8 + 3] = a3;
      orow[c * 8 + 4] = a4; orow[c * 8 + 5] = a5;
      orow[c * 8 + 6] = a6; orow[c * 8 + 7] = a7;
      mnv = fminf(mnv, fminf(fminf(fminf(a0, a1), fminf(a2, a3)),
                             fminf(fminf(a4, a5), fminf(a6, a7))));
      mxv = fmaxf(mxv, fmaxf(fmaxf(fmaxf(a0, a1), fmaxf(a2, a3)),
                             fmaxf(fmaxf(a4, a5), fmaxf(a6, a7))));
    }
  }
#pragma unroll
  for (int off = 32; off > 0; off >>= 1) {
    mnv = fminf(mnv, __shfl_xor(mnv, off, 64));
    mxv = fmaxf(mxv, __shfl_xor(mxv, off, 64));
  }
  const int lane = t & 63, wv = t >> 6;
  if (lane == 0) { red[wv][0] = mnv; red[wv][1] = mxv; }
  __syncthreads();
  if (t == 0) {
    const float m0 = fminf(fminf(red[0][0], red[1][0]), fminf(red[2][0], red[3][0]));
    const float m1 = fmaxf(fmaxf(red[0][1], red[1][1]), fmaxf(red[2][1], red[3][1]));
    atomicMin(&mm[0], __float_as_uint(m0));   // nonneg floats monotone as uints
    atomicMax(&mm[1], __float_as_uint(m1));
  }
}

// ---------------- Stage 2c: normalize (float4) ----------------
__global__ __launch_bounds__(256) void k_norm(const float4* __restrict__ in,
                                              const unsigned int* __restrict__ mm,
                                              float4* __restrict__ out) {
  const int i = blockIdx.x * 256 + threadIdx.x;  // 200704 float4s exactly
  const float mn = __uint_as_float(mm[0]);
  const float mx = __uint_as_float(mm[1]);
  const float inv = 1.f / (mx - mn);
  const float4 v = in[i];
  out[i] = make_float4((v.x - mn) * inv, (v.y - mn) * inv,
                       (v.z - mn) * inv, (v.w - mn) * inv);
}

extern "C" void kernel_launch(void* const* d_in, const int* in_sizes, int n_in,
                              void* d_out, int out_size, void* d_ws, size_t ws_size,
                              hipStream_t stream) {
  const float* emb = (const float*)d_in[0];    // [16,256,3136]
  const float* means = (const float*)d_in[1];  // [3136,256]
  const float* icov = (const float*)d_in[2];   // [3136,256,256]
  float* out = (float*)d_out;                  // [16,224,224]

  char* ws = (char*)d_ws;
  float* dist = (float*)ws;                        // 16*3136 floats   @ 0
  float* tmp1 = (float*)(ws + 204800);             // 16*224*224 floats
  unsigned int* mm = (unsigned int*)(ws + 3416064);

  k_dist<<<NP, 256, 0, stream>>>(emb, means, icov, dist, mm);
  k_blur<<<NB * 4, 256, 0, stream>>>(dist, tmp1, mm);
  k_norm<<<NB * OW * OW / 1024, 256, 0, stream>>>((const float4*)tmp1, mm,
                                                  (float4*)out);
}